// Round 4
// baseline (177.471 us; speedup 1.0000x reference)
//
#include <hip/hip_runtime.h>

#define BT    16
#define NN    10242
#define CC    64
#define KK    9
#define NBR_  7
#define OO    64
#define CK    576
#define MT    32            // rows (nodes) per block
#define RS    584           // LDS itp row stride in bf16 (16B-aligned, bank-spread)
#define KT    18            // K tiles of 32

using frag  = __attribute__((ext_vector_type(8))) short;   // 8 bf16 (4 VGPRs)
using f32x4 = __attribute__((ext_vector_type(4))) float;

static __device__ __forceinline__ unsigned short f2bf(float f) {
    union { float f; unsigned u; } v; v.f = f;
    unsigned r = v.u + 0x7fffu + ((v.u >> 16) & 1u);   // RNE
    return (unsigned short)(r >> 16);
}

// q-permutation shared by producer and weight pack:
//   k in [0,8): q = (k>>2)*256 + c*4 + (k&3);  k==8: q = 512 + c
// wb[((t*4+ct)*64+lane)*8+j] = bf16(w[o][c][k]), q=t*32+(lane>>4)*8+j, o=ct*16+(lane&15)
// i = OUTPUT index -> coalesced 2B writes (combine into full lines); reads scattered (L1/L2-hot).
__global__ void pack_w_kernel(const float* __restrict__ w, unsigned short* __restrict__ wb) {
    int i = blockIdx.x * blockDim.x + threadIdx.x;
    if (i >= KT * 4 * 64 * 8) return;
    int j  = i & 7;
    int l  = (i >> 3) & 63;
    int ct = (i >> 9) & 3;
    int t  = i >> 11;
    int q  = t * 32 + (l >> 4) * 8 + j;
    int o  = ct * 16 + (l & 15);
    int c, k;
    if (q < 512) { c = (q & 255) >> 2; k = (q >> 8) * 4 + (q & 3); }
    else         { c = q - 512;        k = 8; }
    wb[i] = f2bf(w[(o * CC + c) * KK + k]);
}

__global__ __launch_bounds__(256, 3) void sphere_conv_kernel(
    const float* __restrict__ x,      // (BT, N, C)
    const int*   __restrict__ index,  // (N, NBR)
    const float* __restrict__ m,      // (N, NBR, K)
    const unsigned short* __restrict__ wb,  // packed B frags (bf16 bits)
    const float* __restrict__ bias,   // (O,)
    float*       __restrict__ out)    // (BT, N, O)
{
    __shared__ unsigned short itp_s[MT * RS];   // 37376 B
    __shared__ float m_s[MT * 64];              //  8192 B  [ns][t], t<63 valid
    __shared__ int   idx_s[MT * 8];             //  1024 B  [ns][j], j<7 valid
                                                // total 46592 B -> 3 blocks/CU
    const int tid  = threadIdx.x;
    const int bt   = blockIdx.x;                // bt fastest -> XCD L2 locality
    const int n0   = blockIdx.y * MT;
    const int w    = tid >> 6;
    const int lane = tid & 63;

    // ---------------- Phase 0: stage m + index into LDS (coalesced) ---------
    #pragma unroll
    for (int p = 0; p < 8; ++p) {
        const int i  = p * 256 + tid;           // 0..2047
        const int ns = i >> 6, t = i & 63;
        float v = 0.f;
        if (t < 63 && (n0 + ns) < NN)
            v = m[(size_t)(n0 + ns) * 63 + t];  // contiguous per row
        m_s[i] = v;
    }
    {
        const int ns = tid >> 3, j = tid & 7;
        int v = 0;
        if (j < 7 && (n0 + ns) < NN)
            v = index[(n0 + ns) * NBR_ + j];
        idx_s[tid] = v;                         // OOB rows -> idx 0 (safe gather)
    }
    __syncthreads();

    // ---------------- Producer: 8 rows/wave, lane = channel, pipelined ------
    {
        const float* xbt = x + (size_t)bt * NN * CC;
        // prologue: gathers for row 0
        float xv[NBR_];
        {
            const int ns = w * 8;
            #pragma unroll
            for (int j = 0; j < NBR_; ++j) {
                const int id = idx_s[ns * 8 + j];               // LDS broadcast
                xv[j] = xbt[(size_t)id * CC + lane];            // coalesced 256B
            }
        }
        #pragma unroll
        for (int r = 0; r < 8; ++r) {
            const int ns = w * 8 + r;
            // issue next row's gathers early (hide latency under FMAs)
            float nv[NBR_];
            if (r < 7) {
                #pragma unroll
                for (int j = 0; j < NBR_; ++j) {
                    const int id = idx_s[(ns + 1) * 8 + j];
                    nv[j] = xbt[(size_t)id * CC + lane];
                }
            }
            // m row -> registers via uniform ds_read_b128 (broadcast)
            const float4* mr4 = (const float4*)&m_s[ns * 64];
            float4 mv[16];
            #pragma unroll
            for (int t = 0; t < 16; ++t) mv[t] = mr4[t];
            const float* mf = (const float*)&mv[0];

            float acc[KK];
            #pragma unroll
            for (int k = 0; k < KK; ++k) acc[k] = 0.f;
            #pragma unroll
            for (int j = 0; j < NBR_; ++j)
                #pragma unroll
                for (int k = 0; k < KK; ++k)
                    acc[k] = fmaf(xv[j], mf[j * KK + k], acc[k]);

            unsigned short h[KK];
            #pragma unroll
            for (int k = 0; k < KK; ++k) h[k] = f2bf(acc[k]);
            uint2 q0, q1;
            q0.x = (unsigned)h[0] | ((unsigned)h[1] << 16);
            q0.y = (unsigned)h[2] | ((unsigned)h[3] << 16);
            q1.x = (unsigned)h[4] | ((unsigned)h[5] << 16);
            q1.y = (unsigned)h[6] | ((unsigned)h[7] << 16);
            unsigned short* row = &itp_s[ns * RS];
            *(uint2*)(&row[lane * 4])       = q0;               // 8B, 2-way banks
            *(uint2*)(&row[256 + lane * 4]) = q1;
            row[512 + lane] = h[8];

            if (r < 7) {
                #pragma unroll
                for (int j = 0; j < NBR_; ++j) xv[j] = nv[j];
            }
        }
    }
    __syncthreads();

    // ------------- Consumer: wave = 16 rows x 32 cols (2 MFMA / k-tile) -----
    const int rt   = w & 1;
    const int cp   = w >> 1;
    const int am   = lane & 15;
    const int half = lane >> 4;

    f32x4 acc0 = (f32x4){0.f, 0.f, 0.f, 0.f};
    f32x4 acc1 = (f32x4){0.f, 0.f, 0.f, 0.f};

    const unsigned short* arow = &itp_s[(rt * 16 + am) * RS + half * 8];
    const frag* wbf = (const frag*)wb;

    #pragma unroll 6
    for (int t = 0; t < KT; ++t) {
        const frag a  = *(const frag*)(arow + t * 32);        // ds_read_b128
        const frag b0 = wbf[(t * 4 + 2 * cp) * 64 + lane];    // L1/L2-hot
        const frag b1 = wbf[(t * 4 + 2 * cp + 1) * 64 + lane];
        acc0 = __builtin_amdgcn_mfma_f32_16x16x32_bf16(a, b0, acc0, 0, 0, 0);
        acc1 = __builtin_amdgcn_mfma_f32_16x16x32_bf16(a, b1, acc1, 0, 0, 0);
    }

    // ---------------- Epilogue: bias + store ---------------------------------
    // D layout: col = lane&15, row = (lane>>4)*4 + i
    const size_t obase = (size_t)bt * NN * OO;
    #pragma unroll
    for (int cc = 0; cc < 2; ++cc) {
        const int o  = (2 * cp + cc) * 16 + am;
        const float bo = bias[o];
        const f32x4 a = cc ? acc1 : acc0;
        #pragma unroll
        for (int i = 0; i < 4; ++i) {
            const int n = n0 + rt * 16 + half * 4 + i;
            if (n < NN) out[obase + (size_t)n * OO + o] = a[i] + bo;
        }
    }
}

extern "C" void kernel_launch(void* const* d_in, const int* in_sizes, int n_in,
                              void* d_out, int out_size, void* d_ws, size_t ws_size,
                              hipStream_t stream) {
    const float* x      = (const float*)d_in[0];
    const int*   index  = (const int*)  d_in[1];
    const float* m      = (const float*)d_in[2];
    const float* conv_w = (const float*)d_in[3];
    const float* conv_b = (const float*)d_in[4];
    float* out = (float*)d_out;
    unsigned short* wb = (unsigned short*)d_ws;   // 73728 B

    {   // pack weights into MFMA B-fragment order (coalesced writes)
        const int total = KT * 4 * 64 * 8;
        pack_w_kernel<<<(total + 255) / 256, 256, 0, stream>>>(conv_w, wb);
    }
    {   // fused gather + interp + MFMA conv
        dim3 grid(BT, (NN + MT - 1) / MT);        // bt fastest for XCD L2 reuse
        sphere_conv_kernel<<<grid, 256, 0, stream>>>(x, index, m, wb, conv_b, out);
    }
}

// Round 5
// 148.263 us; speedup vs baseline: 1.1970x; 1.1970x over previous
//
#include <hip/hip_runtime.h>

#define BT    16
#define NN    10242
#define CC    64
#define KK    9
#define NBR_  7
#define OO    64
#define CK    576
#define MT    16            // rows (nodes) per block  -> LDS 18.7KB -> 8 blocks/CU
#define RS    584           // LDS itp row stride in bf16 (16B-aligned, bank-spread)
#define KT    18            // K tiles of 32

using frag  = __attribute__((ext_vector_type(8))) short;   // 8 bf16 (4 VGPRs)
using f32x4 = __attribute__((ext_vector_type(4))) float;

static __device__ __forceinline__ unsigned short f2bf(float f) {
    union { float f; unsigned u; } v; v.f = f;
    unsigned r = v.u + 0x7fffu + ((v.u >> 16) & 1u);   // RNE
    return (unsigned short)(r >> 16);
}

// q-permutation shared by producer and weight pack:
//   k in [0,8): q = (k>>2)*256 + c*4 + (k&3);  k==8: q = 512 + c
// wb[((t*4+ct)*64+lane)*8+j] = bf16(w[o][c][k]), q=t*32+(lane>>4)*8+j, o=ct*16+(lane&15)
__global__ void pack_w_kernel(const float* __restrict__ w, unsigned short* __restrict__ wb) {
    int i = blockIdx.x * blockDim.x + threadIdx.x;
    if (i >= KT * 4 * 64 * 8) return;
    int j  = i & 7;
    int l  = (i >> 3) & 63;
    int ct = (i >> 9) & 3;
    int t  = i >> 11;
    int q  = t * 32 + (l >> 4) * 8 + j;
    int o  = ct * 16 + (l & 15);
    int c, k;
    if (q < 512) { c = (q & 255) >> 2; k = (q >> 8) * 4 + (q & 3); }
    else         { c = q - 512;        k = 8; }
    wb[i] = f2bf(w[(o * CC + c) * KK + k]);
}

__global__ __launch_bounds__(256, 6) void sphere_conv_kernel(
    const float* __restrict__ x,      // (BT, N, C)
    const int*   __restrict__ index,  // (N, NBR)
    const float* __restrict__ m,      // (N, NBR, K)
    const unsigned short* __restrict__ wb,  // packed B frags (bf16 bits)
    const float* __restrict__ bias,   // (O,)
    float*       __restrict__ out)    // (BT, N, O)
{
    __shared__ unsigned short itp_s[MT * RS];   // 18688 B -> LDS allows 8 blocks/CU

    const int tid  = threadIdx.x;
    const int bt   = blockIdx.x;                // bt fastest -> XCD L2 locality
    const int n0   = blockIdx.y * MT;
    const int w    = tid >> 6;
    const int lane = tid & 63;

    // ---------------- Producer: 4 rows/wave, lane = channel, full unroll ----
    {
        const float* xbt = x + (size_t)bt * NN * CC;
        #pragma unroll
        for (int r = 0; r < 4; ++r) {
            const int ns = w * 4 + r;
            int n  = n0 + ns;
            // clamp (reads stay in-bounds; junk rows never stored) + force
            // wave-uniform so index/m go through scalar loads (K$/L2)
            int nu = __builtin_amdgcn_readfirstlane(n < NN ? n : (NN - 1));
            const int*   ip = index + nu * NBR_;          // SGPR base
            const float* mp = m + nu * (NBR_ * KK);       // SGPR base
            float xv[NBR_];
            #pragma unroll
            for (int j = 0; j < NBR_; ++j) {
                const int idj = ip[j];                    // s_load
                xv[j] = xbt[(size_t)idj * CC + lane];     // coalesced 256B gather
            }
            float acc[KK];
            #pragma unroll
            for (int k = 0; k < KK; ++k) acc[k] = 0.f;
            #pragma unroll
            for (int j = 0; j < NBR_; ++j)
                #pragma unroll
                for (int k = 0; k < KK; ++k)
                    acc[k] = fmaf(xv[j], mp[j * KK + k], acc[k]);  // m: s_load

            unsigned short h[KK];
            #pragma unroll
            for (int k = 0; k < KK; ++k) h[k] = f2bf(acc[k]);
            uint2 q0, q1;
            q0.x = (unsigned)h[0] | ((unsigned)h[1] << 16);
            q0.y = (unsigned)h[2] | ((unsigned)h[3] << 16);
            q1.x = (unsigned)h[4] | ((unsigned)h[5] << 16);
            q1.y = (unsigned)h[6] | ((unsigned)h[7] << 16);
            unsigned short* row = &itp_s[ns * RS];
            *(uint2*)(&row[lane * 4])       = q0;         // 8B, 2-way banks = free
            *(uint2*)(&row[256 + lane * 4]) = q1;
            row[512 + lane] = h[8];
        }
    }
    __syncthreads();

    // ------------- Consumer: wave = 16 rows x 16 cols (ct = wave id) --------
    const int ct   = w;
    const int am   = lane & 15;
    const int half = lane >> 4;

    f32x4 acc = (f32x4){0.f, 0.f, 0.f, 0.f};

    const unsigned short* arow = &itp_s[am * RS + half * 8];
    const frag* wbf = (const frag*)wb;

    #pragma unroll
    for (int t = 0; t < KT; ++t) {
        const frag a = *(const frag*)(arow + t * 32);       // ds_read_b128
        const frag b = wbf[(t * 4 + ct) * 64 + lane];       // L2-hot
        acc = __builtin_amdgcn_mfma_f32_16x16x32_bf16(a, b, acc, 0, 0, 0);
    }

    // ---------------- Epilogue: bias + store ---------------------------------
    // D layout: col = lane&15, row = (lane>>4)*4 + i
    const size_t obase = (size_t)bt * NN * OO;
    {
        const int o  = ct * 16 + am;
        const float bo = bias[o];
        #pragma unroll
        for (int i = 0; i < 4; ++i) {
            const int n = n0 + half * 4 + i;
            if (n < NN) out[obase + (size_t)n * OO + o] = acc[i] + bo;
        }
    }
}

extern "C" void kernel_launch(void* const* d_in, const int* in_sizes, int n_in,
                              void* d_out, int out_size, void* d_ws, size_t ws_size,
                              hipStream_t stream) {
    const float* x      = (const float*)d_in[0];
    const int*   index  = (const int*)  d_in[1];
    const float* m      = (const float*)d_in[2];
    const float* conv_w = (const float*)d_in[3];
    const float* conv_b = (const float*)d_in[4];
    float* out = (float*)d_out;
    unsigned short* wb = (unsigned short*)d_ws;   // 73728 B

    {   // pack weights into MFMA B-fragment order
        const int total = KT * 4 * 64 * 8;
        pack_w_kernel<<<(total + 255) / 256, 256, 0, stream>>>(conv_w, wb);
    }
    {   // fused gather + interp + MFMA conv
        dim3 grid(BT, (NN + MT - 1) / MT);        // bt fastest for XCD L2 reuse
        sphere_conv_kernel<<<grid, 256, 0, stream>>>(x, index, m, wb, conv_b, out);
    }
}